// Round 1
// baseline (1583.787 us; speedup 1.0000x reference)
//
#include <hip/hip_runtime.h>
#include <math.h>

// ---------------- problem constants ----------------
#define LSEQ   2048
#define DM     512
#define NLAYER 4
#define NMODE  32
#define BATCH  2
#define VOCAB  50257
#define CHUNK  32            // timesteps per scan chunk
#define NCHUNK 64            // LSEQ / CHUNK
#define ROWS   (BATCH*LSEQ)  // 4096
#define PI_F   3.14159265358979323846f

typedef __bf16 bf16_t;
typedef __bf16 bf16x8 __attribute__((ext_vector_type(8)));
typedef float  floatx4 __attribute__((ext_vector_type(4)));

__device__ __forceinline__ float gelu_f(float v) {
  // jax.nn.gelu default (approximate=True, tanh form)
  return 0.5f * v * (1.0f + tanhf(0.7978845608028654f * (v + 0.044715f * v * v * v)));
}
__device__ __forceinline__ float sigmoid_f(float v) {
  return 1.0f / (1.0f + expf(-v));
}

// ---------------- modal parameter prep ----------------
// wcp[(layer*DM+d)*NMODE+n][6] = {w_re, w_im, Cp_re, Cp_im, wT_re, wT_im}
// w  = exp(dt*A_n),  Cp = (C_re + i C_im)*(w-1)/A_n,  wT = w^CHUNK
__global__ __launch_bounds__(256) void prep_kernel(
    const float* __restrict__ log_dt, const float* __restrict__ C_re,
    const float* __restrict__ C_im, float* __restrict__ wcp) {
  int idx = blockIdx.x * 256 + threadIdx.x;       // NLAYER*DM*NMODE
  int n  = idx & (NMODE - 1);
  int ld = idx >> 5;                               // layer*DM + d
  float dt = expf(log_dt[ld]);
  float ar = -0.5f * dt;
  float ai = PI_F * (float)n * dt;
  float em = expf(ar);
  float wr = em * cosf(ai), wi = em * sinf(ai);
  float pn = PI_F * (float)n;
  float inv = 1.0f / (0.25f + pn * pn);
  float m1r = wr - 1.0f, m1i = wi;
  float qr = (-0.5f * m1r + pn * m1i) * inv;       // (w-1)*conj(A)/|A|^2
  float qi = (-0.5f * m1i - pn * m1r) * inv;
  float cre = C_re[idx], cim = C_im[idx];
  float cpr = cre * qr - cim * qi;
  float cpi = cre * qi + cim * qr;
  float emT = expf(ar * (float)CHUNK);
  float aT  = ai * (float)CHUNK;
  float wTr = emT * cosf(aT), wTi = emT * sinf(aT);
  float* o = wcp + (size_t)idx * 6;
  o[0] = wr; o[1] = wi; o[2] = cpr; o[3] = cpi; o[4] = wTr; o[5] = wTi;
}

// ---------------- embedding ----------------
__global__ __launch_bounds__(256) void embed_kernel(
    const int* __restrict__ ids, const float* __restrict__ tok,
    const float* __restrict__ pos, float* __restrict__ x) {
  int idx = blockIdx.x * 256 + threadIdx.x;   // ROWS*DM
  int d  = idx & (DM - 1);
  int bl = idx >> 9;
  int l  = bl & (LSEQ - 1);
  int id = ids[bl];
  x[idx] = tok[(size_t)id * DM + d] + pos[(size_t)l * DM + d];
}

// ---------------- fp32 -> bf16 convert ----------------
__global__ __launch_bounds__(256) void cvt_bf16_kernel(
    const float* __restrict__ src, bf16_t* __restrict__ dst, int n) {
  int idx = blockIdx.x * 256 + threadIdx.x;
  if (idx < n) dst[idx] = (bf16_t)src[idx];
}

// ---------------- scan phase 1: local chunk end-states ----------------
// E[((b*DM+d)*NCHUNK+c)*NMODE+n] = sum_{j<CHUNK} w^(CHUNK-1-j) x[c*CHUNK+j]
__global__ __launch_bounds__(256) void scan_phase1_kernel(
    const float* __restrict__ x, const float* __restrict__ wcp,
    float2* __restrict__ E, int layer) {
  int idx = blockIdx.x * 256 + threadIdx.x;   // BATCH*NCHUNK*DM, d fastest
  int d  = idx & (DM - 1);
  int bc = idx >> 9;
  int c  = bc & (NCHUNK - 1);
  int b  = bc >> 6;
  const float* xp = x + ((size_t)(b * LSEQ + c * CHUNK)) * DM + d;
  float xr[CHUNK];
  #pragma unroll
  for (int t = 0; t < CHUNK; t++) xr[t] = xp[(size_t)t * DM];
  const float* wp = wcp + (size_t)(layer * DM + d) * NMODE * 6;
  float2* Ep = E + ((size_t)(b * DM + d) * NCHUNK + c) * NMODE;
  #pragma unroll 1
  for (int np = 0; np < NMODE / 2; np++) {
    int n0 = np * 2;
    float w0r = wp[n0*6+0], w0i = wp[n0*6+1];
    float w1r = wp[n0*6+6], w1i = wp[n0*6+7];
    float s0r = 0.f, s0i = 0.f, s1r = 0.f, s1i = 0.f;
    #pragma unroll
    for (int t = 0; t < CHUNK; t++) {
      float xt = xr[t];
      float a0r = fmaf(w0r, s0r, fmaf(-w0i, s0i, xt));
      float a0i = fmaf(w0r, s0i, w0i * s0r);
      float a1r = fmaf(w1r, s1r, fmaf(-w1i, s1i, xt));
      float a1i = fmaf(w1r, s1i, w1i * s1r);
      s0r = a0r; s0i = a0i; s1r = a1r; s1i = a1i;
    }
    Ep[n0]     = make_float2(s0r, s0i);
    Ep[n0 + 1] = make_float2(s1r, s1i);
  }
}

// ---------------- scan combine: exclusive prefix across chunks ----------------
// in-place: E[c] <- carry-in state for chunk c (state at end of chunk c-1)
__global__ __launch_bounds__(256) void scan_combine_kernel(
    const float* __restrict__ wcp, float2* __restrict__ E, int layer) {
  int idx = blockIdx.x * 256 + threadIdx.x;   // BATCH*DM*NMODE, n fastest
  int n  = idx & (NMODE - 1);
  int bd = idx >> 5;                           // b*DM + d
  int d  = bd & (DM - 1);
  const float* wp = wcp + ((size_t)(layer * DM + d) * NMODE + n) * 6;
  float wTr = wp[4], wTi = wp[5];
  float2* Ep = E + (size_t)bd * NCHUNK * NMODE + n;
  float sr = 0.f, si = 0.f;
  for (int c = 0; c < NCHUNK; c++) {
    float2 e = Ep[(size_t)c * NMODE];
    Ep[(size_t)c * NMODE] = make_float2(sr, si);
    float tr = fmaf(wTr, sr, -(wTi * si)) + e.x;
    float ti = fmaf(wTr, si, wTi * sr) + e.y;
    sr = tr; si = ti;
  }
}

// ---------------- scan phase 2: outputs + skip + gelu -> bf16 ----------------
__global__ __launch_bounds__(256) void scan_phase2_kernel(
    const float* __restrict__ x, const float* __restrict__ wcp,
    const float2* __restrict__ E, const float* __restrict__ skipD,
    bf16_t* __restrict__ yb, int layer) {
  int idx = blockIdx.x * 256 + threadIdx.x;   // BATCH*NCHUNK*DM, d fastest
  int d  = idx & (DM - 1);
  int bc = idx >> 9;
  int c  = bc & (NCHUNK - 1);
  int b  = bc >> 6;
  const float* xp = x + ((size_t)(b * LSEQ + c * CHUNK)) * DM + d;
  float xr[CHUNK];
  #pragma unroll
  for (int t = 0; t < CHUNK; t++) xr[t] = xp[(size_t)t * DM];
  float ya[CHUNK];
  #pragma unroll
  for (int t = 0; t < CHUNK; t++) ya[t] = 0.f;
  const float* wp = wcp + (size_t)(layer * DM + d) * NMODE * 6;
  const float2* Ep = E + ((size_t)(b * DM + d) * NCHUNK + c) * NMODE;
  #pragma unroll 1
  for (int np = 0; np < NMODE / 2; np++) {
    int n0 = np * 2;
    float w0r = wp[n0*6+0], w0i = wp[n0*6+1];
    float c0r = wp[n0*6+2], c0i = wp[n0*6+3];
    float w1r = wp[n0*6+6], w1i = wp[n0*6+7];
    float c1r = wp[n0*6+8], c1i = wp[n0*6+9];
    float2 e0 = Ep[n0], e1 = Ep[n0 + 1];
    float s0r = e0.x, s0i = e0.y, s1r = e1.x, s1i = e1.y;
    #pragma unroll
    for (int t = 0; t < CHUNK; t++) {
      float xt = xr[t];
      float a0r = fmaf(w0r, s0r, fmaf(-w0i, s0i, xt));
      float a0i = fmaf(w0r, s0i, w0i * s0r);
      float a1r = fmaf(w1r, s1r, fmaf(-w1i, s1i, xt));
      float a1i = fmaf(w1r, s1i, w1i * s1r);
      s0r = a0r; s0i = a0i; s1r = a1r; s1i = a1i;
      float acc = fmaf(c0r, s0r, ya[t]);
      acc = fmaf(-c0i, s0i, acc);
      acc = fmaf(c1r, s1r, acc);
      ya[t] = fmaf(-c1i, s1i, acc);
    }
  }
  float sk = skipD[layer * DM + d];
  bf16_t* yp = yb + ((size_t)(b * LSEQ + c * CHUNK)) * DM + d;
  #pragma unroll
  for (int t = 0; t < CHUNK; t++) {
    float v = fmaf(xr[t], sk, 2.0f * ya[t]);
    yp[(size_t)t * DM] = (bf16_t)gelu_f(v);
  }
}

// ---------------- GEMM: C(M,Nreal) = A(M,K) * B(N,K)^T + bias ----------------
// m97 structure: 128x128 tile, BK=32, 4 waves of 4x4 16x16x32 bf16 MFMA,
// global_load_lds width-16 staging. B rows clamped, stores predicated (N edge).
__global__ __launch_bounds__(256) void gemm_bt_kernel(
    const bf16_t* __restrict__ A, const bf16_t* __restrict__ B,
    float* __restrict__ C, const float* __restrict__ bias, int Nreal, int K) {
  __shared__ __align__(16) bf16_t As[128 * 32];
  __shared__ __align__(16) bf16_t Bs[128 * 32];
  int tid = threadIdx.x;
  int lid = tid & 63;
  int w   = tid >> 6;
  int tileM = blockIdx.y * 128;
  int tileN = blockIdx.x * 128;
  int wm = w & 1, wn = w >> 1;

  floatx4 acc[4][4];
  floatx4 zero = {0.f, 0.f, 0.f, 0.f};
  #pragma unroll
  for (int i = 0; i < 4; i++)
    #pragma unroll
    for (int j = 0; j < 4; j++) acc[i][j] = zero;

  for (int k0 = 0; k0 < K; k0 += 32) {
    #pragma unroll
    for (int i = 0; i < 2; i++) {
      int flat = i * 256 + tid;
      int row  = flat >> 2;
      int kg   = (flat & 3) * 8;
      const bf16_t* ga = A + (size_t)(tileM + row) * K + (k0 + kg);
      int brow = tileN + row;
      if (brow >= Nreal) brow = Nreal - 1;     // clamp: value discarded by store predicate
      const bf16_t* gb = B + (size_t)brow * K + (k0 + kg);
      __builtin_amdgcn_global_load_lds(
          (const __attribute__((address_space(1))) void*)ga,
          (__attribute__((address_space(3))) void*)(&As[flat * 8]), 16, 0, 0);
      __builtin_amdgcn_global_load_lds(
          (const __attribute__((address_space(1))) void*)gb,
          (__attribute__((address_space(3))) void*)(&Bs[flat * 8]), 16, 0, 0);
    }
    __syncthreads();   // drains vmcnt (async LDS loads) per __syncthreads semantics

    bf16x8 af[4], bfr[4];
    #pragma unroll
    for (int i = 0; i < 4; i++) {
      af[i]  = *(const bf16x8*)&As[((wm * 64 + i * 16 + (lid & 15)) * 32) + ((lid >> 4) * 8)];
      bfr[i] = *(const bf16x8*)&Bs[((wn * 64 + i * 16 + (lid & 15)) * 32) + ((lid >> 4) * 8)];
    }
    #pragma unroll
    for (int i = 0; i < 4; i++)
      #pragma unroll
      for (int j = 0; j < 4; j++)
        acc[i][j] = __builtin_amdgcn_mfma_f32_16x16x32_bf16(af[i], bfr[j], acc[i][j], 0, 0, 0);
    __syncthreads();
  }

  // C/D layout: col = lane&15 (N dim), row = (lane>>4)*4 + reg (M dim)
  #pragma unroll
  for (int i = 0; i < 4; i++) {
    int m = tileM + wm * 64 + i * 16 + (lid >> 4) * 4;
    #pragma unroll
    for (int j = 0; j < 4; j++) {
      int n = tileN + wn * 64 + j * 16 + (lid & 15);
      if (n < Nreal) {
        float bv = bias ? bias[n] : 0.f;
        #pragma unroll
        for (int r = 0; r < 4; r++)
          C[(size_t)(m + r) * Nreal + n] = acc[i][j][r] + bv;
      }
    }
  }
}

// ---------------- GLU + residual: x += z[:,:D] * sigmoid(z[:,D:]) ----------------
__global__ __launch_bounds__(256) void glu_res_kernel(
    const float* __restrict__ z, float* __restrict__ x) {
  int idx = blockIdx.x * 256 + threadIdx.x;   // ROWS*DM
  int d = idx & (DM - 1);
  int m = idx >> 9;
  float a = z[(size_t)m * (2 * DM) + d];
  float g = z[(size_t)m * (2 * DM) + DM + d];
  x[idx] += a * sigmoid_f(g);
}

// ---------------- LayerNorm -> bf16 ----------------
__global__ __launch_bounds__(256) void ln_kernel(
    const float* __restrict__ x, const float* __restrict__ g,
    const float* __restrict__ bta, bf16_t* __restrict__ xn) {
  int m = blockIdx.x;
  int tid = threadIdx.x;
  int lid = tid & 63, w = tid >> 6;
  const float* xp = x + (size_t)m * DM;
  float v0 = xp[tid], v1 = xp[tid + 256];
  __shared__ float sw[4];
  __shared__ float bcast;
  float s = v0 + v1;
  #pragma unroll
  for (int o = 32; o > 0; o >>= 1) s += __shfl_down(s, o);
  if (lid == 0) sw[w] = s;
  __syncthreads();
  if (tid == 0) bcast = (sw[0] + sw[1] + sw[2] + sw[3]) * (1.0f / DM);
  __syncthreads();
  float mu = bcast;
  float d0 = v0 - mu, d1 = v1 - mu;
  float q = d0 * d0 + d1 * d1;
  #pragma unroll
  for (int o = 32; o > 0; o >>= 1) q += __shfl_down(q, o);
  __syncthreads();
  if (lid == 0) sw[w] = q;
  __syncthreads();
  if (tid == 0) bcast = rsqrtf((sw[0] + sw[1] + sw[2] + sw[3]) * (1.0f / DM) + 1e-5f);
  __syncthreads();
  float rs = bcast;
  xn[(size_t)m * DM + tid]       = (bf16_t)(d0 * rs * g[tid] + bta[tid]);
  xn[(size_t)m * DM + tid + 256] = (bf16_t)(d1 * rs * g[tid + 256] + bta[tid + 256]);
}

// ---------------- launch ----------------
extern "C" void kernel_launch(void* const* d_in, const int* in_sizes, int n_in,
                              void* d_out, int out_size, void* d_ws, size_t ws_size,
                              hipStream_t stream) {
  const int*   ids   = (const int*)  d_in[0];
  const float* tok   = (const float*)d_in[1];
  const float* pos   = (const float*)d_in[2];
  const float* logdt = (const float*)d_in[3];
  const float* cre   = (const float*)d_in[4];
  const float* cim   = (const float*)d_in[5];
  const float* skipD = (const float*)d_in[6];
  const float* outw  = (const float*)d_in[7];
  const float* outb  = (const float*)d_in[8];
  const float* lng   = (const float*)d_in[9];
  const float* lnb   = (const float*)d_in[10];
  const float* headw = (const float*)d_in[11];
  float* logits = (float*)d_out;

  // workspace layout (aliasing is deliberate & stream-ordered safe):
  //  [0,8M)    x residual stream (fp32)
  //  [8M,24M)  z GEMM1 output (fp32, 16M)  ALIASES  E scan states (float2, 16M)
  //            (E dead before GEMM1 writes z each layer)
  //  [24M,28M) yb bf16 GEMM1 input  ALIASES  xn bf16 head-GEMM input
  //  [28M,32M) wb: out_w as bf16
  //  [32M,34M) wcp modal params
  //  [34M,~83M) hb: head_w as bf16
  char* ws = (char*)d_ws;
  float*  x   = (float*)(ws);
  float*  z   = (float*)(ws + (8u  << 20));
  float2* E   = (float2*)(ws + (8u << 20));
  bf16_t* yb  = (bf16_t*)(ws + (24u << 20));
  bf16_t* xn  = (bf16_t*)(ws + (24u << 20));
  bf16_t* wb  = (bf16_t*)(ws + (28u << 20));
  float*  wcp = (float*)(ws + (32u << 20));
  bf16_t* hb  = (bf16_t*)(ws + (34u << 20));

  prep_kernel<<<(NLAYER * DM * NMODE) / 256, 256, 0, stream>>>(logdt, cre, cim, wcp);
  cvt_bf16_kernel<<<(NLAYER * 2 * DM * DM) / 256, 256, 0, stream>>>(outw, wb, NLAYER * 2 * DM * DM);
  cvt_bf16_kernel<<<(VOCAB * DM + 255) / 256, 256, 0, stream>>>(headw, hb, VOCAB * DM);
  embed_kernel<<<(ROWS * DM) / 256, 256, 0, stream>>>(ids, tok, pos, x);

  for (int layer = 0; layer < NLAYER; layer++) {
    scan_phase1_kernel<<<(BATCH * NCHUNK * DM) / 256, 256, 0, stream>>>(x, wcp, E, layer);
    scan_combine_kernel<<<(BATCH * DM * NMODE) / 256, 256, 0, stream>>>(wcp, E, layer);
    scan_phase2_kernel<<<(BATCH * NCHUNK * DM) / 256, 256, 0, stream>>>(x, wcp, E, skipD, yb, layer);
    dim3 g1((2 * DM) / 128, ROWS / 128);
    gemm_bt_kernel<<<g1, 256, 0, stream>>>(yb, wb + (size_t)layer * 2 * DM * DM, z,
                                           outb + layer * 2 * DM, 2 * DM, DM);
    glu_res_kernel<<<(ROWS * DM) / 256, 256, 0, stream>>>(z, x);
  }

  ln_kernel<<<ROWS, 256, 0, stream>>>(x, lng, lnb, xn);
  dim3 g2((VOCAB + 127) / 128, ROWS / 128);
  gemm_bt_kernel<<<g2, 256, 0, stream>>>(xn, hb, logits, nullptr, VOCAB, DM);
}